// Round 11
// baseline (234.184 us; speedup 1.0000x reference)
//
#include <hip/hip_runtime.h>

#define MU 5
static constexpr int Hh = 1024, Ww = 1024, Bb = 8;
static constexpr int NPIX = Bb * Hh * Ww;
static constexpr int TPB = 256;
static constexpr int SOBEL_BLOCKS = NPIX / 4 / TPB;     // 8192 (4 px/thread)
static constexpr int PY = 16;                            // V: rows/thread
static constexpr int PXH = 4;                            // H: cols/thread
static constexpr int VBLK = NPIX / PY / TPB;             // 2048
static constexpr int HBLK = NPIX / PXH / TPB;            // 8192

__device__ __forceinline__ float rcp_fast(float x) { return __builtin_amdgcn_rcpf(x); }
__device__ __forceinline__ float rsq_fast(float x) { return __builtin_amdgcn_rsqf(x); }

// Bijective XCD-chunk swizzle (NB % 8 == 0): each XCD owns a contiguous
// chunk -> stencil halo reuse stays within one XCD's L2.
template <int NB>
__device__ __forceinline__ int xcd_swizzle(int bid) {
    return (bid & 7) * (NB / 8) + (bid >> 3);
}

// Shared sobel 4-px gradient helper: rows y-1..y+1, cols x0-1..x0+4.
__device__ __forceinline__ void sobel4(const float* __restrict__ p,
                                       int y, int x0,
                                       float gx[4], float gy[4]) {
    float c[3][6];
    #pragma unroll
    for (int r = 0; r < 3; ++r) {
        int yy = y - 1 + r;
        bool okr = (yy >= 0) && (yy < Hh);
        const float* row = p + (okr ? yy : 0) * Ww;
        float4 v = okr ? *(const float4*)(row + x0) : make_float4(0.f, 0.f, 0.f, 0.f);
        c[r][1] = v.x; c[r][2] = v.y; c[r][3] = v.z; c[r][4] = v.w;
        c[r][0] = (okr && x0 > 0)      ? row[x0 - 1] : 0.0f;
        c[r][5] = (okr && x0 + 4 < Ww) ? row[x0 + 4] : 0.0f;
    }
    float S[6], D[6];
    #pragma unroll
    for (int cc = 0; cc < 6; ++cc) {
        S[cc] = c[0][cc] + 2.0f * c[1][cc] + c[2][cc];
        D[cc] = c[2][cc] - c[0][cc];
    }
    #pragma unroll
    for (int k = 0; k < 4; ++k) {
        gx[k] = S[k + 2] - S[k];
        gy[k] = D[k] + 2.0f * D[k + 1] + D[k + 2];
    }
}

// ---- Pass 1: global max of g2 only. NO array writes. ----
__global__ __launch_bounds__(TPB) void maxg2_kernel(
        const float* __restrict__ in, float* __restrict__ partials) {
    int id = blockIdx.x * TPB + threadIdx.x;
    int xq = id & (Ww / 4 - 1);
    int x0 = xq * 4;
    int y  = (id >> 8) & (Hh - 1);
    int b  = id >> 18;
    const float* p = in + ((size_t)b << 20);

    float gx[4], gy[4];
    sobel4(p, y, x0, gx, gy);

    float vmax = 0.0f;
    #pragma unroll
    for (int k = 0; k < 4; ++k)
        vmax = fmaxf(vmax, gx[k] * gx[k] + gy[k] * gy[k]);

    #pragma unroll
    for (int off = 32; off; off >>= 1) vmax = fmaxf(vmax, __shfl_xor(vmax, off));
    __shared__ float smax[4];
    int lane = threadIdx.x & 63, wid = threadIdx.x >> 6;
    if (lane == 0) smax[wid] = vmax;
    __syncthreads();
    if (threadIdx.x == 0)
        partials[blockIdx.x] = fmaxf(fmaxf(smax[0], smax[1]), fmaxf(smax[2], smax[3]));
}

__global__ void max_reduce_kernel(const float* __restrict__ partials,
                                  float* __restrict__ scale_out) {
    float v = 0.0f;
    for (int i = threadIdx.x; i < SOBEL_BLOCKS; i += 1024)
        v = fmaxf(v, partials[i]);
    #pragma unroll
    for (int off = 32; off; off >>= 1) v = fmaxf(v, __shfl_xor(v, off));
    __shared__ float smax[16];
    int lane = threadIdx.x & 63, wid = threadIdx.x >> 6;
    if (lane == 0) smax[wid] = v;
    __syncthreads();
    if (threadIdx.x == 0) {
        float m = smax[0];
        #pragma unroll
        for (int i = 1; i < 16; ++i) m = fmaxf(m, smax[i]);
        *scale_out = 1.0f / sqrtf(m);   // max(|g|) = sqrt(max(g2))
    }
}

// ---- Pass 2: recompute sobel (input L3-hot), write tang + E directly.
// E = exp(2*scale*mag); per tap (tanh(scale*(mY-mX))+1)*0.5 == E_Y/(E_X+E_Y).
__global__ __launch_bounds__(TPB) void sobelE_kernel(
        const float* __restrict__ in, float2* __restrict__ tang,
        float* __restrict__ E, const float* __restrict__ scalep) {
    int id = blockIdx.x * TPB + threadIdx.x;
    int xq = id & (Ww / 4 - 1);
    int x0 = xq * 4;
    int y  = (id >> 8) & (Hh - 1);
    int b  = id >> 18;
    const float* p = in + ((size_t)b << 20);
    float k2 = 2.0f * (*scalep);

    float gx[4], gy[4];
    sobel4(p, y, x0, gx, gy);

    float2 tg[4];
    float  eg[4];
    #pragma unroll
    for (int k = 0; k < 4; ++k) {
        float g2 = gx[k] * gx[k] + gy[k] * gy[k];
        float irs = rsq_fast(g2);
        float m   = (g2 > 0.0f) ? g2 * irs : 0.0f;   // sqrt
        float inv = (g2 > 0.0f) ? irs : 1.0f;        // 1/sqrt
        tg[k] = make_float2(-gy[k] * inv, gx[k] * inv);
        eg[k] = __expf(k2 * m);
    }

    int idx = (b << 20) + y * Ww + x0;
    *(float4*)&E[idx] = make_float4(eg[0], eg[1], eg[2], eg[3]);
    float4* tp = (float4*)&tang[idx];
    tp[0] = make_float4(tg[0].x, tg[0].y, tg[1].x, tg[1].y);
    tp[1] = make_float4(tg[2].x, tg[2].y, tg[3].x, tg[3].y);
}

// ---- V pass: PY=16 vertically-consecutive outputs per thread ----
__global__ __launch_bounds__(TPB) void etf_v(const float2* __restrict__ src,
                                             float2* __restrict__ dst,
                                             const float* __restrict__ E) {
    int bid = xcd_swizzle<VBLK>((int)blockIdx.x);
    int gid = bid * TPB + threadIdx.x;
    int x = gid & (Ww - 1);
    int yg = (gid >> 10) & (Hh / PY - 1);
    int b = gid >> 16;
    int y0 = yg * PY;
    int base = b << 20;

    float2 t[PY + 10];
    float  e[PY + 10];
    if (yg >= 1 && yg <= Hh / PY - 2) {          // uniform per block
        #pragma unroll
        for (int r = 0; r < PY + 10; ++r) {
            int j = base + (y0 - MU + r) * Ww + x;
            t[r] = src[j];
            e[r] = E[j];
        }
    } else {
        #pragma unroll
        for (int r = 0; r < PY + 10; ++r) {
            int row = y0 - MU + r;
            bool ok = (row >= 0) && (row < Hh);
            int j = base + (ok ? row : 0) * Ww + x;
            t[r] = ok ? src[j] : make_float2(0.0f, 0.0f);
            e[r] = ok ? E[j] : 1.0f;             // d=0 anyway; keep rcp finite
        }
    }

    #pragma unroll
    for (int k = 0; k < PY; ++k) {
        float2 tX = t[k + MU];
        float  eX = e[k + MU];
        float ax = 0.0f, ay = 0.0f;
        #pragma unroll
        for (int i = 0; i <= 2 * MU; ++i) {
            float2 tY = t[k + i];
            float  eY = e[k + i];
            float d = tX.x * tY.x + tX.y * tY.y;
            float w = eY * rcp_fast(eX + eY) * d;
            ax += tY.x * w;
            ay += tY.y * w;
        }
        dst[base + (y0 + k) * Ww + x] = make_float2(ax, ay);
    }
}

// ---- H pass: PXH=4 outputs per thread ----
template <bool FINAL>
__global__ __launch_bounds__(TPB) void etf_h(const float2* __restrict__ src,
                                             float2* __restrict__ dstI,
                                             float* __restrict__ dstP,
                                             const float* __restrict__ E) {
    int bid = xcd_swizzle<HBLK>((int)blockIdx.x);
    int gid = bid * TPB + threadIdx.x;
    int xq = gid & (Ww / PXH - 1);       // 0..255
    int x0 = xq * PXH;
    int y = (gid >> 8) & (Hh - 1);
    int b = gid >> 18;
    int rowbase = (b << 20) + y * Ww;

    float2 t[PXH + 10];
    float  e[PXH + 10];
    if (xq >= 2 && xq <= Ww / PXH - 3) { // interior (x0-5 >= 0, x0+8 <= 1023)
        #pragma unroll
        for (int r = 0; r < PXH + 10; ++r) {
            int j = rowbase + x0 - MU + r;
            t[r] = src[j];
            e[r] = E[j];
        }
    } else {                             // border: masked scalar path
        #pragma unroll
        for (int r = 0; r < PXH + 10; ++r) {
            int col = x0 - MU + r;
            bool ok = (col >= 0) && (col < Ww);
            int j = rowbase + (ok ? col : 0);
            t[r] = ok ? src[j] : make_float2(0.0f, 0.0f);
            e[r] = ok ? E[j] : 1.0f;
        }
    }

    float ox[PXH], oy[PXH];
    #pragma unroll
    for (int k = 0; k < PXH; ++k) {
        float2 tX = t[k + MU];
        float  eX = e[k + MU];
        float ax = 0.0f, ay = 0.0f;
        #pragma unroll
        for (int i = 0; i <= 2 * MU; ++i) {
            float2 tY = t[k + i];
            float  eY = e[k + i];
            float d = tX.x * tY.x + tX.y * tY.y;
            float w = eY * rcp_fast(eX + eY) * d;
            ax += tY.x * w;
            ay += tY.y * w;
        }
        float n2 = ax * ax + ay * ay;
        float inv = (n2 > 0.0f) ? rsq_fast(n2) : 1.0f;
        ox[k] = ax * inv;
        oy[k] = ay * inv;
    }

    if (FINAL) {
        *(float4*)&dstP[((size_t)(b * 2 + 0) << 20) + y * Ww + x0] =
            make_float4(ox[0], ox[1], ox[2], ox[3]);
        *(float4*)&dstP[((size_t)(b * 2 + 1) << 20) + y * Ww + x0] =
            make_float4(oy[0], oy[1], oy[2], oy[3]);
    } else {
        float4* dp = (float4*)&dstI[rowbase + x0];
        dp[0] = make_float4(ox[0], oy[0], ox[1], oy[1]);
        dp[1] = make_float4(ox[2], oy[2], ox[3], oy[3]);
    }
}

extern "C" void kernel_launch(void* const* d_in, const int* in_sizes, int n_in,
                              void* d_out, int out_size, void* d_ws, size_t ws_size,
                              hipStream_t stream) {
    const float* in = (const float*)d_in[0];
    float* out = (float*)d_out;
    char* ws = (char*)d_ws;

    float* magE = (float*)ws;                                           // 32 MB (E)
    float2* tA = (float2*)(ws + (size_t)NPIX * sizeof(float));          // 64 MB
    float* partials = (float*)(ws + (size_t)NPIX * sizeof(float)
                                  + (size_t)NPIX * sizeof(float2));
    float* scalep = partials + SOBEL_BLOCKS;
    float2* tOut = (float2*)out;

    maxg2_kernel<<<SOBEL_BLOCKS, TPB, 0, stream>>>(in, partials);
    max_reduce_kernel<<<1, 1024, 0, stream>>>(partials, scalep);
    sobelE_kernel<<<SOBEL_BLOCKS, TPB, 0, stream>>>(in, tOut, magE, scalep);

    // iteration 1
    etf_v<<<VBLK, TPB, 0, stream>>>(tOut, tA, magE);
    etf_h<false><<<HBLK, TPB, 0, stream>>>(tA, tOut, nullptr, magE);
    // iteration 2
    etf_v<<<VBLK, TPB, 0, stream>>>(tOut, tA, magE);
    etf_h<false><<<HBLK, TPB, 0, stream>>>(tA, tOut, nullptr, magE);
    // iteration 3
    etf_v<<<VBLK, TPB, 0, stream>>>(tOut, tA, magE);
    etf_h<true ><<<HBLK, TPB, 0, stream>>>(tA, nullptr, out, magE);
}